// Round 4
// baseline (382.308 us; speedup 1.0000x reference)
//
#include <hip/hip_runtime.h>
#include <hip/hip_bf16.h>
#include <hip/hip_fp16.h>
#include <math.h>

#define N_NODES 50000
#define N_EDGES 800000
#define HID 64
#define NBK 196          // buckets of 256 nodes
#define EPB 1024         // edges per hist/scatter block
#define SB  ((N_EDGES + EPB - 1) / EPB)   // 782
#define FLAT (NBK * SB)  // 153272 flattened (bucket-major) histogram entries
#define SCAN_B ((FLAT + 255) / 256)  // 599

#define QKVS0_BLKS 3125
#define SCORE_BLKS ((N_EDGES * 4) / 256)   // 12500, exact

// fused prep grid partition
#define LN0_BLKS   6250
#define HIST_BLKS  SB
#define WP0_BLKS   32    // 16*1*512 / 256
#define WP12_BLKS  64    // 16*2*512 / 256
#define PREP_BLKS  (LN0_BLKS + HIST_BLKS + WP0_BLKS + 2 * WP12_BLKS)

typedef __attribute__((ext_vector_type(8))) short short8;
typedef __attribute__((ext_vector_type(4))) float float4v;
typedef __attribute__((ext_vector_type(2))) float float2v;

__device__ __forceinline__ unsigned short f32_to_bf16_rne(float f) {
    unsigned int u = __float_as_uint(f);
    unsigned int r = u + 0x7fffu + ((u >> 16) & 1u);
    return (unsigned short)(r >> 16);
}

// fp8 e4m3fn (OCP on gfx950) helpers: HW cvt instructions.
__device__ __forceinline__ unsigned int f32_to_fp8_byte(float f) {
    return (unsigned int)__builtin_amdgcn_cvt_pk_fp8_f32(f, f, 0, false) & 0xffu;
}
template <bool HI>
__device__ __forceinline__ float2v fp8x2_to_f32(unsigned int w) {
    return __builtin_amdgcn_cvt_pk_f32_fp8((int)w, HI);
}
__device__ __forceinline__ float2 h2_to_f32(unsigned int w) {
    __half2 h = *reinterpret_cast<__half2*>(&w);
    return __half22float2(h);
}

// ---------------------------------------------------------------------------
// Device helpers for the fused prep kernel.
__device__ __forceinline__ void ln0_body(int b, int t,
        const float* __restrict__ x, const float* __restrict__ g,
        const float* __restrict__ bb, float* __restrict__ h0) {
    int lane = t & 63;
    int n = b * 8 + (t >> 6) * 2 + (lane >> 5);
    int c = lane & 31;
    float v = x[n * 32 + c];
    float s = v;
    #pragma unroll
    for (int off = 1; off < 32; off <<= 1) s += __shfl_xor(s, off);
    float mu = s * (1.0f / 32.0f);
    float d = v - mu;
    float vs = d * d;
    #pragma unroll
    for (int off = 1; off < 32; off <<= 1) vs += __shfl_xor(vs, off);
    float var = vs * (1.0f / 32.0f);
    h0[n * 32 + c] = d * rsqrtf(var + 1e-5f) * g[c] + bb[c];
}

__device__ __forceinline__ void wprep_body(int idx, int KS,
        const float* __restrict__ Wq, const float* __restrict__ Wk,
        const float* __restrict__ Wv, const float* __restrict__ Ws,
        unsigned short* __restrict__ Wp) {
    int j = idx & 7;
    int lane = (idx >> 3) & 63;
    int ts = idx >> 9;            // tile*KS + s
    int s = ts % KS;
    int tile = ts / KS;
    int which = tile >> 2;
    int slice = tile & 3;
    int k = s * 32 + ((lane >> 4) * 8) + j;
    int col = slice * 16 + (lane & 15);
    const float* W = (which == 0) ? Wq : (which == 1) ? Wk : (which == 2) ? Wv : Ws;
    Wp[idx] = f32_to_bf16_rne(W[k * 64 + col]);
}

// ---------------------------------------------------------------------------
// Fused prep: ln0 + per-block bucket histogram + 3x weight pack.
__global__ __launch_bounds__(256) void prep_kernel(
        const float* __restrict__ x, const float* __restrict__ ln0g,
        const float* __restrict__ ln0b, float* __restrict__ h0,
        const int* __restrict__ dst, int* __restrict__ ghist,
        const float* __restrict__ Wq0, const float* __restrict__ Wk0,
        const float* __restrict__ Wv0, const float* __restrict__ Ws0,
        unsigned short* __restrict__ Wp0,
        const float* __restrict__ Wq1, const float* __restrict__ Wk1,
        const float* __restrict__ Wv1, const float* __restrict__ Ws1,
        unsigned short* __restrict__ Wp1,
        const float* __restrict__ Wq2, const float* __restrict__ Wk2,
        const float* __restrict__ Wv2, const float* __restrict__ Ws2,
        unsigned short* __restrict__ Wp2) {
    __shared__ int hist[NBK];
    int b = blockIdx.x;
    int t = threadIdx.x;
    if (b < LN0_BLKS) {
        ln0_body(b, t, x, ln0g, ln0b, h0);
    } else if (b < LN0_BLKS + HIST_BLKS) {
        int i = b - LN0_BLKS;
        for (int k = t; k < NBK; k += 256) hist[k] = 0;
        __syncthreads();
        int e0 = i * EPB;
        #pragma unroll
        for (int r = 0; r < EPB / 256; r++) {
            int e = e0 + r * 256 + t;
            if (e < N_EDGES) atomicAdd(&hist[dst[e] >> 8], 1);
        }
        __syncthreads();
        for (int k = t; k < NBK; k += 256) ghist[k * SB + i] = hist[k];
    } else if (b < LN0_BLKS + HIST_BLKS + WP0_BLKS) {
        int idx = (b - LN0_BLKS - HIST_BLKS) * 256 + t;
        wprep_body(idx, 1, Wq0, Wk0, Wv0, Ws0, Wp0);
    } else if (b < LN0_BLKS + HIST_BLKS + WP0_BLKS + WP12_BLKS) {
        int idx = (b - LN0_BLKS - HIST_BLKS - WP0_BLKS) * 256 + t;
        wprep_body(idx, 2, Wq1, Wk1, Wv1, Ws1, Wp1);
    } else {
        int idx = (b - LN0_BLKS - HIST_BLKS - WP0_BLKS - WP12_BLKS) * 256 + t;
        wprep_body(idx, 2, Wq2, Wk2, Wv2, Ws2, Wp2);
    }
}

// ---------------------------------------------------------------------------
// CSR build scans (deterministic, no global atomics).
__global__ void scan1_kernel(const int* __restrict__ ghist, int* __restrict__ csum) {
    int f = blockIdx.x * 256 + threadIdx.x;
    int v = (f < FLAT) ? ghist[f] : 0;
    #pragma unroll
    for (int off = 1; off < 64; off <<= 1) v += __shfl_xor(v, off);
    __shared__ int ws[4];
    if ((threadIdx.x & 63) == 0) ws[threadIdx.x >> 6] = v;
    __syncthreads();
    if (threadIdx.x == 0) csum[blockIdx.x] = ws[0] + ws[1] + ws[2] + ws[3];
}

__global__ void scan2_kernel(const int* __restrict__ csum, int* __restrict__ coff,
                             int* __restrict__ bbase, int* __restrict__ row_ptr) {
    int lane = threadIdx.x;
    int carry = 0;
    for (int base = 0; base < SCAN_B; base += 64) {
        int i = base + lane;
        int v = (i < SCAN_B) ? csum[i] : 0;
        int incl = v;
        #pragma unroll
        for (int off = 1; off < 64; off <<= 1) {
            int tt = __shfl_up(incl, off);
            if (lane >= off) incl += tt;
        }
        if (i < SCAN_B) coff[i] = carry + incl - v;
        carry += __shfl(incl, 63);
    }
    if (lane == 0) { bbase[NBK] = N_EDGES; row_ptr[N_NODES] = N_EDGES; }
}

__global__ void scan3_kernel(const int* __restrict__ ghist, const int* __restrict__ coff,
                             int* __restrict__ goff, int* __restrict__ bbase) {
    int f = blockIdx.x * 256 + threadIdx.x;
    int lane = threadIdx.x & 63;
    int w = threadIdx.x >> 6;
    int v = (f < FLAT) ? ghist[f] : 0;
    int incl = v;
    #pragma unroll
    for (int off = 1; off < 64; off <<= 1) {
        int tt = __shfl_up(incl, off);
        if (lane >= off) incl += tt;
    }
    __shared__ int ws[4];
    if (lane == 63) ws[w] = incl;
    __syncthreads();
    int woff = 0;
    #pragma unroll
    for (int k = 0; k < 4; k++) if (k < w) woff += ws[k];
    int excl = coff[blockIdx.x] + woff + incl - v;
    if (f < FLAT) {
        goff[f] = excl;
        if (f % SB == 0) bbase[f / SB] = excl;
    }
}

// ---------------------------------------------------------------------------
// Q/K/V/Skip projection body via MFMA. Block = 16 nodes; wave w owns the
// 16-col slice w of each of Q,K,V,S. fp32 accum; biases in fp32.
// Outputs: QS = (bf16(S)<<16)|bf16(Q*scale)  (stream, R1-proven precision)
//          K8 = fp8 e4m3 row of 64B (1 line/edge in score kernel)
//          Vh = fp16 row of 128B (2 lines/edge in agg kernel)
template <int D>
__device__ __forceinline__ void qkvs_body(int bid, int t,
        const float* __restrict__ h,
        const unsigned short* __restrict__ Wp,
        const float* __restrict__ bq, const float* __restrict__ bk,
        const float* __restrict__ bv, float scale,
        unsigned int* __restrict__ QS,
        unsigned int* __restrict__ K8, uint2* __restrict__ Vh) {
    constexpr int KS = D / 32;
    int lane = t & 63;
    int w = t >> 6;
    int n0 = bid * 16;
    int n16 = lane & 15;
    int quad = lane >> 4;
    int col = w * 16 + n16;

    short8 afrag[KS];
    #pragma unroll
    for (int s = 0; s < KS; s++) {
        const float* hp = &h[(n0 + n16) * D + s * 32 + quad * 8];
        float4 a0 = *(const float4*)hp;
        float4 a1 = *(const float4*)(hp + 4);
        short8 af;
        af[0] = (short)f32_to_bf16_rne(a0.x);
        af[1] = (short)f32_to_bf16_rne(a0.y);
        af[2] = (short)f32_to_bf16_rne(a0.z);
        af[3] = (short)f32_to_bf16_rne(a0.w);
        af[4] = (short)f32_to_bf16_rne(a1.x);
        af[5] = (short)f32_to_bf16_rne(a1.y);
        af[6] = (short)f32_to_bf16_rne(a1.z);
        af[7] = (short)f32_to_bf16_rne(a1.w);
        afrag[s] = af;
    }

    float4v accs[4];
    #pragma unroll
    for (int which = 0; which < 4; which++) {
        float4v acc = {0.0f, 0.0f, 0.0f, 0.0f};
        int tile = which * 4 + w;
        #pragma unroll
        for (int s = 0; s < KS; s++) {
            short8 bfrag = *(const short8*)&Wp[((tile * KS + s) * 64 + lane) * 8];
            acc = __builtin_amdgcn_mfma_f32_16x16x32_bf16(afrag[s], bfrag, acc, 0, 0, 0);
        }
        accs[which] = acc;
    }

    float bqc = bq[col], bkc = bk[col], bvc = bv[col];
    int j = n16 & 3;                    // byte/half position within 4-channel word
    int mword = (col >> 2);             // 4-channel word index 0..15

    #pragma unroll
    for (int r = 0; r < 4; r++) {
        int node = n0 + quad * 4 + r;
        unsigned int qw = f32_to_bf16_rne((accs[0][r] + bqc) * scale);
        unsigned int sw = f32_to_bf16_rne(accs[3][r]);
        QS[node * 64 + col] = (sw << 16) | qw;
        // fp8-pack K: 4 consecutive channels -> one dword, via shfl-OR
        unsigned int ku = f32_to_fp8_byte(accs[1][r] + bkc) << (8 * j);
        ku |= __shfl_xor(ku, 1); ku |= __shfl_xor(ku, 2);
        // fp16-pack V: 4 consecutive channels -> uint2 {c0|c1<<16, c2|c3<<16}
        unsigned int hb = (unsigned int)__half_as_ushort(__float2half_rn(accs[2][r] + bvc));
        unsigned int vx = (j < 2) ? (hb << (16 * j)) : 0u;
        unsigned int vy = (j >= 2) ? (hb << (16 * (j - 2))) : 0u;
        vx |= __shfl_xor(vx, 1); vx |= __shfl_xor(vx, 2);
        vy |= __shfl_xor(vy, 1); vy |= __shfl_xor(vy, 2);
        if (j == 0) {
            K8[node * 16 + mword] = ku;
            Vh[node * 16 + mword] = make_uint2(vx, vy);
        }
    }
}

template <int D>
__global__ __launch_bounds__(256) void qkvs_mfma_kernel(
        const float* __restrict__ h,
        const unsigned short* __restrict__ Wp,
        const float* __restrict__ bq, const float* __restrict__ bk,
        const float* __restrict__ bv, float scale,
        unsigned int* __restrict__ QS,
        unsigned int* __restrict__ K8, uint2* __restrict__ Vh) {
    qkvs_body<D>(blockIdx.x, threadIdx.x, h, Wp, bq, bk, bv, scale, QS, K8, Vh);
}

// ---------------------------------------------------------------------------
// Fused scatter + layer-0 QKVS (independent work; fills the CUs).
__global__ __launch_bounds__(256) void scatter_qkvs0_kernel(
        const int* __restrict__ src, const int* __restrict__ dst,
        const int* __restrict__ goff, int2* __restrict__ ebkt,
        const float* __restrict__ h, const unsigned short* __restrict__ Wp,
        const float* __restrict__ bq, const float* __restrict__ bk,
        const float* __restrict__ bv, float scale,
        unsigned int* __restrict__ QS,
        unsigned int* __restrict__ K8, uint2* __restrict__ Vh) {
    __shared__ int hist[NBK];
    int t = threadIdx.x;
    if (blockIdx.x < SB) {
        int i = blockIdx.x;
        for (int k = t; k < NBK; k += 256) hist[k] = 0;
        __syncthreads();
        int e0 = i * EPB;
        #pragma unroll
        for (int r = 0; r < EPB / 256; r++) {
            int e = e0 + r * 256 + t;
            if (e < N_EDGES) {
                int s = src[e], d = dst[e];
                int k = d >> 8;
                int rank = atomicAdd(&hist[k], 1);
                ebkt[goff[k * SB + i] + rank] = make_int2(s, d);
            }
        }
    } else {
        qkvs_body<32>(blockIdx.x - SB, t, h, Wp, bq, bk, bv, scale, QS, K8, Vh);
    }
}

// bucket_build now emits colb2 = (src, dst) pairs in CSR order, so the
// edge-parallel score kernel gets both endpoints with one coalesced load.
__global__ __launch_bounds__(256) void bucket_build_kernel(
        const int2* __restrict__ ebkt, const int* __restrict__ bbase,
        int* __restrict__ row_ptr, int2* __restrict__ colb2) {
    __shared__ int ldeg[256];
    __shared__ int lcur[256];
    __shared__ int wsum[4];
    int b = blockIdx.x;
    int t = threadIdx.x;
    int cbase = bbase[b];
    int cnt = bbase[b + 1] - cbase;

    ldeg[t] = 0;
    __syncthreads();
    for (int i = t; i < cnt; i += 256) {
        int2 e = ebkt[cbase + i];
        atomicAdd(&ldeg[e.y & 255], 1);
    }
    __syncthreads();

    int lane = t & 63;
    int w = t >> 6;
    int v = ldeg[t];
    int incl = v;
    #pragma unroll
    for (int off = 1; off < 64; off <<= 1) {
        int tt = __shfl_up(incl, off);
        if (lane >= off) incl += tt;
    }
    if (lane == 63) wsum[w] = incl;
    __syncthreads();
    int woff = 0;
    #pragma unroll
    for (int k = 0; k < 4; k++) if (k < w) woff += wsum[k];
    int excl = woff + incl - v;

    int node = b * 256 + t;
    if (node < N_NODES) row_ptr[node] = cbase + excl;
    lcur[t] = excl;
    __syncthreads();

    for (int i = t; i < cnt; i += 256) {
        int2 e = ebkt[cbase + i];
        int r = atomicAdd(&lcur[e.y & 255], 1);
        colb2[cbase + r] = e;
    }
}

// ---------------------------------------------------------------------------
// Phase A: edge-parallel score+exp. lane = (edge, slot); slot = head (H=4)
// or quarter-of-dot (H=1). Grid covers 800k*4 lanes exactly. Removes the
// per-node kernel's 4x-duplicated exp, all score shuffles, and the
// rowptr->colb->bpermute->K-gather chain (K chain here: colb2 -> K, 1 hop).
template <int HEADS>
__global__ __launch_bounds__(256) void score_kernel(
        const unsigned int* __restrict__ QS,
        const unsigned int* __restrict__ K8,
        const int2* __restrict__ colb2,
        float* __restrict__ p) {
    int gid = blockIdx.x * 256 + threadIdx.x;
    int e = gid >> 2;
    int slot = gid & 3;
    int2 ed = colb2[e];
    const unsigned int* qp = &QS[(size_t)ed.y * 64 + slot * 16];
    uint4 qa = *(const uint4*)qp;
    uint4 qb = *(const uint4*)(qp + 4);
    uint4 qc = *(const uint4*)(qp + 8);
    uint4 qd = *(const uint4*)(qp + 12);
    uint4 kw = *(const uint4*)&K8[(size_t)ed.x * 16 + slot * 4];

    float2v k0 = fp8x2_to_f32<false>(kw.x), k1 = fp8x2_to_f32<true>(kw.x);
    float2v k2 = fp8x2_to_f32<false>(kw.y), k3 = fp8x2_to_f32<true>(kw.y);
    float2v k4 = fp8x2_to_f32<false>(kw.z), k5 = fp8x2_to_f32<true>(kw.z);
    float2v k6 = fp8x2_to_f32<false>(kw.w), k7 = fp8x2_to_f32<true>(kw.w);

    float t;
    t =      __uint_as_float(qa.x << 16) * k0.x;
    t = fmaf(__uint_as_float(qa.y << 16), k0.y, t);
    t = fmaf(__uint_as_float(qa.z << 16), k1.x, t);
    t = fmaf(__uint_as_float(qa.w << 16), k1.y, t);
    t = fmaf(__uint_as_float(qb.x << 16), k2.x, t);
    t = fmaf(__uint_as_float(qb.y << 16), k2.y, t);
    t = fmaf(__uint_as_float(qb.z << 16), k3.x, t);
    t = fmaf(__uint_as_float(qb.w << 16), k3.y, t);
    t = fmaf(__uint_as_float(qc.x << 16), k4.x, t);
    t = fmaf(__uint_as_float(qc.y << 16), k4.y, t);
    t = fmaf(__uint_as_float(qc.z << 16), k5.x, t);
    t = fmaf(__uint_as_float(qc.w << 16), k5.y, t);
    t = fmaf(__uint_as_float(qd.x << 16), k6.x, t);
    t = fmaf(__uint_as_float(qd.y << 16), k6.y, t);
    t = fmaf(__uint_as_float(qd.z << 16), k7.x, t);
    t = fmaf(__uint_as_float(qd.w << 16), k7.y, t);

    if (HEADS == 1) {
        t += __shfl_xor(t, 1);
        t += __shfl_xor(t, 2);
    }
    float pv = __expf(t);
    if (HEADS == 4) {
        p[(size_t)e * 4 + slot] = pv;
    } else {
        if (slot == 0) p[e] = pv;
    }
}

// ---------------------------------------------------------------------------
// Phase B: per-node V-aggregation + skip + LayerNorm (+res/relu/HEAD-MLP).
// Loop has NO cross-lane ops: colb2 loaded directly per lane (no bpermute),
// p read sequentially in CSR order (stream), V gather (2 lines/edge), 4 fma.
template <int HEADS, bool RES, bool RELU, bool HEAD>
__global__ __launch_bounds__(256) void agg_kernel(
                           const unsigned int* __restrict__ QS,
                           const uint2* __restrict__ Vh,
                           const float* __restrict__ p,
                           const int2* __restrict__ colb2,
                           const int* __restrict__ row_ptr,
                           const float* __restrict__ g, const float* __restrict__ b,
                           const float* __restrict__ h_in, float* __restrict__ h_out,
                           const float* __restrict__ Wr1, const float* __restrict__ br1,
                           const float* __restrict__ Wr2, const float* __restrict__ br2,
                           const float* __restrict__ Wt1, const float* __restrict__ bt1,
                           const float* __restrict__ Wt2, const float* __restrict__ bt2,
                           float* __restrict__ out) {
    int lane = threadIdx.x & 63;
    int m = lane & 15;
    int grp = lane >> 4;
    int n = blockIdx.x * 4 + (threadIdx.x >> 6);
    int hsel = m >> 2;

    int beg = row_ptr[n], end = row_ptr[n + 1];

    float ssum = 0.0f;
    float acc0 = 0.0f, acc1 = 0.0f, acc2 = 0.0f, acc3 = 0.0f;

    for (int base = beg; base < end; base += 16) {
        #pragma unroll
        for (int c = 0; c < 4; c++) {
            int idx = base + c * 4 + grp;
            bool ok = idx < end;
            int s = 0;
            float pv = 0.0f;
            if (ok) {
                s = colb2[idx].x;
                pv = (HEADS == 4) ? p[(size_t)idx * 4 + hsel] : p[idx];
            }
            uint2 va = Vh[(size_t)s * 16 + m];
            float2 v0 = h2_to_f32(va.x), v1 = h2_to_f32(va.y);
            ssum += pv;
            acc0 = fmaf(pv, v0.x, acc0);
            acc1 = fmaf(pv, v0.y, acc1);
            acc2 = fmaf(pv, v1.x, acc2);
            acc3 = fmaf(pv, v1.y, acc3);
        }
    }

    #pragma unroll
    for (int off = 16; off < 64; off <<= 1) {
        ssum += __shfl_xor(ssum, off);
        acc0 += __shfl_xor(acc0, off);
        acc1 += __shfl_xor(acc1, off);
        acc2 += __shfl_xor(acc2, off);
        acc3 += __shfl_xor(acc3, off);
    }

    float inv = 1.0f / (ssum + 1e-16f);
    uint4 qsw = *(const uint4*)&QS[(size_t)n * 64 + 4 * m];
    float o0 = fmaf(acc0, inv, __uint_as_float(qsw.x & 0xffff0000u));
    float o1 = fmaf(acc1, inv, __uint_as_float(qsw.y & 0xffff0000u));
    float o2 = fmaf(acc2, inv, __uint_as_float(qsw.z & 0xffff0000u));
    float o3 = fmaf(acc3, inv, __uint_as_float(qsw.w & 0xffff0000u));

    float s = (o0 + o1) + (o2 + o3);
    #pragma unroll
    for (int off = 1; off < 16; off <<= 1) s += __shfl_xor(s, off);
    float mu = s * (1.0f / 64.0f);
    float d0 = o0 - mu, d1 = o1 - mu, d2 = o2 - mu, d3 = o3 - mu;
    float vs = (d0 * d0 + d1 * d1) + (d2 * d2 + d3 * d3);
    #pragma unroll
    for (int off = 1; off < 16; off <<= 1) vs += __shfl_xor(vs, off);
    float rstd = rsqrtf(vs * (1.0f / 64.0f) + 1e-5f);

    float4 gv = *(const float4*)&g[4 * m];
    float4 bv = *(const float4*)&b[4 * m];
    float y0 = d0 * rstd * gv.x + bv.x;
    float y1 = d1 * rstd * gv.y + bv.y;
    float y2 = d2 * rstd * gv.z + bv.z;
    float y3 = d3 * rstd * gv.w + bv.w;
    if (RES) {
        float4 rv = *(const float4*)&h_in[n * 64 + 4 * m];
        y0 = fmaf(0.1f, rv.x, y0);
        y1 = fmaf(0.1f, rv.y, y1);
        y2 = fmaf(0.1f, rv.z, y2);
        y3 = fmaf(0.1f, rv.w, y3);
    }
    if (RELU) {
        y0 = fmaxf(y0, 0.0f); y1 = fmaxf(y1, 0.0f);
        y2 = fmaxf(y2, 0.0f); y3 = fmaxf(y3, 0.0f);
    }

    if (!HEAD) {
        if (grp == 0) {
            float4 yv = make_float4(y0, y1, y2, y3);
            *(float4*)&h_out[n * 64 + 4 * m] = yv;
        }
    } else {
        __shared__ float sh[4][HID];
        int wave = threadIdx.x >> 6;
        if (grp == 0) {
            float4 yv = make_float4(y0, y1, y2, y3);
            *(float4*)&sh[wave][4 * m] = yv;
        }
        __syncthreads();
        int half = lane >> 5;
        int j = lane & 31;
        const float* W1 = half ? Wt1 : Wr1;
        const float* b1 = half ? bt1 : br1;
        const float* W2 = half ? Wt2 : Wr2;
        const float* b2v = half ? bt2 : br2;
        float a = b1[j];
        #pragma unroll 8
        for (int i = 0; i < 64; i++) a = fmaf(sh[wave][i], W1[i * 32 + j], a);
        a = fmaxf(a, 0.0f);
        float r = a * W2[j];
        #pragma unroll
        for (int off = 1; off < 32; off <<= 1) r += __shfl_xor(r, off);
        if (j == 0) out[n * 2 + half] = r + b2v[0];
    }
}

// ---------------------------------------------------------------------------
extern "C" void kernel_launch(void* const* d_in, const int* in_sizes, int n_in,
                              void* d_out, int out_size, void* d_ws, size_t ws_size,
                              hipStream_t stream) {
    const float* x    = (const float*)d_in[0];
    const int*   ei   = (const int*)d_in[1];
    const int*   src  = ei;
    const int*   dst  = ei + N_EDGES;
    const float* ln0g = (const float*)d_in[2];
    const float* ln0b = (const float*)d_in[3];

    const float* P[27];
    for (int i = 0; i < 27; i++) P[i] = (const float*)d_in[4 + i];
    const float* Wr1 = (const float*)d_in[31];
    const float* br1 = (const float*)d_in[32];
    const float* Wr2 = (const float*)d_in[33];
    const float* br2 = (const float*)d_in[34];
    const float* Wt1 = (const float*)d_in[35];
    const float* bt1 = (const float*)d_in[36];
    const float* Wt2 = (const float*)d_in[37];
    const float* bt2 = (const float*)d_in[38];

    float* out = (float*)d_out;

    // workspace layout
    float* hbuf0 = (float*)d_ws;                 // N*64
    float* hbuf1 = hbuf0 + N_NODES * 64;         // N*64
    unsigned int* QSb = (unsigned int*)(hbuf1 + N_NODES * 64); // N*64 uint
    unsigned int* K8 = QSb + N_NODES * 64;       // N*16 uint (64B fp8 rows)
    uint2* Vh    = (uint2*)(K8 + N_NODES * 16);  // N*16 uint2 (128B fp16 rows)
    float* pbuf  = (float*)(Vh + N_NODES * 16);  // E*4 f32 (edge-head probs)
    int* row_ptr = (int*)(pbuf + (size_t)N_EDGES * 4); // N+2 (pad for colb2 align)
    int2* colb2  = (int2*)(row_ptr + (N_NODES + 2));   // E int2 (src,dst)
    int* ghist   = (int*)(colb2 + N_EDGES);      // FLAT
    int* goff    = ghist + FLAT;                 // FLAT
    int* csum    = goff + FLAT;                  // SCAN_B
    int* coff    = csum + SCAN_B;                // SCAN_B
    int* bbase   = coff + SCAN_B;                // NBK+1
    unsigned short* Wp0 = (unsigned short*)(bbase + NBK + 1); // 16*1*512
    unsigned short* Wp1 = Wp0 + 16 * 1 * 512;                 // 16*2*512
    unsigned short* Wp2 = Wp1 + 16 * 2 * 512;                 // 16*2*512
    // ebkt aliases hbuf1 (dead until agg0 writes it): E int2 = 6.4 MB < 12.8 MB
    int2* ebkt = (int2*)hbuf1;

    // ---- fused prep (ln0 + bucket hist + weight packs) ----
    prep_kernel<<<PREP_BLKS, 256, 0, stream>>>(x, ln0g, ln0b, hbuf0,
        dst, ghist,
        P[0],  P[2],  P[4],  P[6],  Wp0,
        P[9],  P[11], P[13], P[15], Wp1,
        P[18], P[20], P[22], P[24], Wp2);
    // ---- CSR build (deterministic counting sort, separate kernels) ----
    scan1_kernel<<<SCAN_B, 256, 0, stream>>>(ghist, csum);
    scan2_kernel<<<1, 64, 0, stream>>>(csum, coff, bbase, row_ptr);
    scan3_kernel<<<SCAN_B, 256, 0, stream>>>(ghist, coff, goff, bbase);
    // ---- scatter + layer-0 QKVS fused (independent work, fills the CUs) ----
    scatter_qkvs0_kernel<<<SB + QKVS0_BLKS, 256, 0, stream>>>(src, dst, goff, ebkt,
        hbuf0, Wp0, P[1], P[3], P[5], 0.25f, QSb, K8, Vh);
    bucket_build_kernel<<<NBK, 256, 0, stream>>>(ebkt, bbase, row_ptr, colb2);

    // ---- layer 0: 32 -> 64, heads=4, no residual, relu ----
    score_kernel<4><<<SCORE_BLKS, 256, 0, stream>>>(QSb, K8, colb2, pbuf);
    agg_kernel<4, false, true, false><<<12500, 256, 0, stream>>>(QSb, Vh, pbuf,
        colb2, row_ptr, P[7], P[8], nullptr, hbuf1,
        Wr1, br1, Wr2, br2, Wt1, bt1, Wt2, bt2, out);

    // ---- layer 1: 64 -> 64, heads=4, residual, relu ----
    qkvs_mfma_kernel<64><<<3125, 256, 0, stream>>>(hbuf1, Wp1,
        P[10], P[12], P[14], 0.25f, QSb, K8, Vh);
    score_kernel<4><<<SCORE_BLKS, 256, 0, stream>>>(QSb, K8, colb2, pbuf);
    agg_kernel<4, true, true, false><<<12500, 256, 0, stream>>>(QSb, Vh, pbuf,
        colb2, row_ptr, P[16], P[17], hbuf1, hbuf0,
        Wr1, br1, Wr2, br2, Wt1, bt1, Wt2, bt2, out);

    // ---- layer 2: 64 -> 64, heads=1, residual, no relu + fused MLP heads ----
    qkvs_mfma_kernel<64><<<3125, 256, 0, stream>>>(hbuf0, Wp2,
        P[19], P[21], P[23], 0.125f, QSb, K8, Vh);
    score_kernel<1><<<SCORE_BLKS, 256, 0, stream>>>(QSb, K8, colb2, pbuf);
    agg_kernel<1, true, false, true><<<12500, 256, 0, stream>>>(QSb, Vh, pbuf,
        colb2, row_ptr, P[25], P[26], hbuf0, hbuf1,
        Wr1, br1, Wr2, br2, Wt1, bt1, Wt2, bt2, out);
}

// Round 5
// 362.483 us; speedup vs baseline: 1.0547x; 1.0547x over previous
//
#include <hip/hip_runtime.h>
#include <hip/hip_bf16.h>
#include <hip/hip_fp16.h>
#include <math.h>

#define N_NODES 50000
#define N_EDGES 800000
#define HID 64
#define NBK 196          // buckets of 256 nodes
#define EPB 1024         // edges per hist/scatter block
#define SB  ((N_EDGES + EPB - 1) / EPB)   // 782
#define FLAT (NBK * SB)  // 153272 flattened (bucket-major) histogram entries
#define SCAN_B ((FLAT + 255) / 256)  // 599

#define QKVS0_BLKS 3125

// fused prep grid partition
#define LN0_BLKS   6250
#define HIST_BLKS  SB
#define WP0_BLKS   32    // 16*1*512 / 256
#define WP12_BLKS  64    // 16*2*512 / 256
#define PREP_BLKS  (LN0_BLKS + HIST_BLKS + WP0_BLKS + 2 * WP12_BLKS)

typedef __attribute__((ext_vector_type(8))) short short8;
typedef __attribute__((ext_vector_type(4))) float float4v;
typedef __attribute__((ext_vector_type(2))) float float2v;

__device__ __forceinline__ unsigned short f32_to_bf16_rne(float f) {
    unsigned int u = __float_as_uint(f);
    unsigned int r = u + 0x7fffu + ((u >> 16) & 1u);
    return (unsigned short)(r >> 16);
}

// fp8 e4m3fn (OCP on gfx950) helpers: HW cvt instructions.
__device__ __forceinline__ unsigned int f32_to_fp8_byte(float f) {
    return (unsigned int)__builtin_amdgcn_cvt_pk_fp8_f32(f, f, 0, false) & 0xffu;
}
template <bool HI>
__device__ __forceinline__ float2v fp8x2_to_f32(unsigned int w) {
    return __builtin_amdgcn_cvt_pk_f32_fp8((int)w, HI);
}
__device__ __forceinline__ float2 h2_to_f32(unsigned int w) {
    __half2 h = *reinterpret_cast<__half2*>(&w);
    return __half22float2(h);
}

// ---------------------------------------------------------------------------
// Device helpers for the fused prep kernel.
__device__ __forceinline__ void ln0_body(int b, int t,
        const float* __restrict__ x, const float* __restrict__ g,
        const float* __restrict__ bb, float* __restrict__ h0) {
    int lane = t & 63;
    int n = b * 8 + (t >> 6) * 2 + (lane >> 5);
    int c = lane & 31;
    float v = x[n * 32 + c];
    float s = v;
    #pragma unroll
    for (int off = 1; off < 32; off <<= 1) s += __shfl_xor(s, off);
    float mu = s * (1.0f / 32.0f);
    float d = v - mu;
    float vs = d * d;
    #pragma unroll
    for (int off = 1; off < 32; off <<= 1) vs += __shfl_xor(vs, off);
    float var = vs * (1.0f / 32.0f);
    h0[n * 32 + c] = d * rsqrtf(var + 1e-5f) * g[c] + bb[c];
}

__device__ __forceinline__ void wprep_body(int idx, int KS,
        const float* __restrict__ Wq, const float* __restrict__ Wk,
        const float* __restrict__ Wv, const float* __restrict__ Ws,
        unsigned short* __restrict__ Wp) {
    int j = idx & 7;
    int lane = (idx >> 3) & 63;
    int ts = idx >> 9;            // tile*KS + s
    int s = ts % KS;
    int tile = ts / KS;
    int which = tile >> 2;
    int slice = tile & 3;
    int k = s * 32 + ((lane >> 4) * 8) + j;
    int col = slice * 16 + (lane & 15);
    const float* W = (which == 0) ? Wq : (which == 1) ? Wk : (which == 2) ? Wv : Ws;
    Wp[idx] = f32_to_bf16_rne(W[k * 64 + col]);
}

// ---------------------------------------------------------------------------
// Fused prep: ln0 + per-block bucket histogram + 3x weight pack.
__global__ __launch_bounds__(256) void prep_kernel(
        const float* __restrict__ x, const float* __restrict__ ln0g,
        const float* __restrict__ ln0b, float* __restrict__ h0,
        const int* __restrict__ dst, int* __restrict__ ghist,
        const float* __restrict__ Wq0, const float* __restrict__ Wk0,
        const float* __restrict__ Wv0, const float* __restrict__ Ws0,
        unsigned short* __restrict__ Wp0,
        const float* __restrict__ Wq1, const float* __restrict__ Wk1,
        const float* __restrict__ Wv1, const float* __restrict__ Ws1,
        unsigned short* __restrict__ Wp1,
        const float* __restrict__ Wq2, const float* __restrict__ Wk2,
        const float* __restrict__ Wv2, const float* __restrict__ Ws2,
        unsigned short* __restrict__ Wp2) {
    __shared__ int hist[NBK];
    int b = blockIdx.x;
    int t = threadIdx.x;
    if (b < LN0_BLKS) {
        ln0_body(b, t, x, ln0g, ln0b, h0);
    } else if (b < LN0_BLKS + HIST_BLKS) {
        int i = b - LN0_BLKS;
        for (int k = t; k < NBK; k += 256) hist[k] = 0;
        __syncthreads();
        int e0 = i * EPB;
        #pragma unroll
        for (int r = 0; r < EPB / 256; r++) {
            int e = e0 + r * 256 + t;
            if (e < N_EDGES) atomicAdd(&hist[dst[e] >> 8], 1);
        }
        __syncthreads();
        for (int k = t; k < NBK; k += 256) ghist[k * SB + i] = hist[k];
    } else if (b < LN0_BLKS + HIST_BLKS + WP0_BLKS) {
        int idx = (b - LN0_BLKS - HIST_BLKS) * 256 + t;
        wprep_body(idx, 1, Wq0, Wk0, Wv0, Ws0, Wp0);
    } else if (b < LN0_BLKS + HIST_BLKS + WP0_BLKS + WP12_BLKS) {
        int idx = (b - LN0_BLKS - HIST_BLKS - WP0_BLKS) * 256 + t;
        wprep_body(idx, 2, Wq1, Wk1, Wv1, Ws1, Wp1);
    } else {
        int idx = (b - LN0_BLKS - HIST_BLKS - WP0_BLKS - WP12_BLKS) * 256 + t;
        wprep_body(idx, 2, Wq2, Wk2, Wv2, Ws2, Wp2);
    }
}

// ---------------------------------------------------------------------------
// CSR build scans (deterministic, no global atomics).
__global__ void scan1_kernel(const int* __restrict__ ghist, int* __restrict__ csum) {
    int f = blockIdx.x * 256 + threadIdx.x;
    int v = (f < FLAT) ? ghist[f] : 0;
    #pragma unroll
    for (int off = 1; off < 64; off <<= 1) v += __shfl_xor(v, off);
    __shared__ int ws[4];
    if ((threadIdx.x & 63) == 0) ws[threadIdx.x >> 6] = v;
    __syncthreads();
    if (threadIdx.x == 0) csum[blockIdx.x] = ws[0] + ws[1] + ws[2] + ws[3];
}

__global__ void scan2_kernel(const int* __restrict__ csum, int* __restrict__ coff,
                             int* __restrict__ bbase, int* __restrict__ row_ptr) {
    int lane = threadIdx.x;
    int carry = 0;
    for (int base = 0; base < SCAN_B; base += 64) {
        int i = base + lane;
        int v = (i < SCAN_B) ? csum[i] : 0;
        int incl = v;
        #pragma unroll
        for (int off = 1; off < 64; off <<= 1) {
            int tt = __shfl_up(incl, off);
            if (lane >= off) incl += tt;
        }
        if (i < SCAN_B) coff[i] = carry + incl - v;
        carry += __shfl(incl, 63);
    }
    if (lane == 0) { bbase[NBK] = N_EDGES; row_ptr[N_NODES] = N_EDGES; }
}

__global__ void scan3_kernel(const int* __restrict__ ghist, const int* __restrict__ coff,
                             int* __restrict__ goff, int* __restrict__ bbase) {
    int f = blockIdx.x * 256 + threadIdx.x;
    int lane = threadIdx.x & 63;
    int w = threadIdx.x >> 6;
    int v = (f < FLAT) ? ghist[f] : 0;
    int incl = v;
    #pragma unroll
    for (int off = 1; off < 64; off <<= 1) {
        int tt = __shfl_up(incl, off);
        if (lane >= off) incl += tt;
    }
    __shared__ int ws[4];
    if (lane == 63) ws[w] = incl;
    __syncthreads();
    int woff = 0;
    #pragma unroll
    for (int k = 0; k < 4; k++) if (k < w) woff += ws[k];
    int excl = coff[blockIdx.x] + woff + incl - v;
    if (f < FLAT) {
        goff[f] = excl;
        if (f % SB == 0) bbase[f / SB] = excl;
    }
}

// ---------------------------------------------------------------------------
// Q/K/V/Skip projection body via MFMA. Block = 16 nodes; wave w owns the
// 16-col slice w of each of Q,K,V,S. fp32 accum; biases in fp32.
// Outputs (precision budget: streams free, gathers compressed):
//   Qf, Sf : f32 streams (Q pre-scaled by 1/sqrt(C))
//   K8     : fp8 e4m3 row of 64B  (1 line/edge)
//   Vh     : fp16 row of 128B     (2 lines/edge)
template <int D>
__device__ __forceinline__ void qkvs_body(int bid, int t,
        const float* __restrict__ h,
        const unsigned short* __restrict__ Wp,
        const float* __restrict__ bq, const float* __restrict__ bk,
        const float* __restrict__ bv, float scale,
        float* __restrict__ Qf, float* __restrict__ Sf,
        unsigned int* __restrict__ K8, uint2* __restrict__ Vh) {
    constexpr int KS = D / 32;
    int lane = t & 63;
    int w = t >> 6;
    int n0 = bid * 16;
    int n16 = lane & 15;
    int quad = lane >> 4;
    int col = w * 16 + n16;

    short8 afrag[KS];
    #pragma unroll
    for (int s = 0; s < KS; s++) {
        const float* hp = &h[(n0 + n16) * D + s * 32 + quad * 8];
        float4 a0 = *(const float4*)hp;
        float4 a1 = *(const float4*)(hp + 4);
        short8 af;
        af[0] = (short)f32_to_bf16_rne(a0.x);
        af[1] = (short)f32_to_bf16_rne(a0.y);
        af[2] = (short)f32_to_bf16_rne(a0.z);
        af[3] = (short)f32_to_bf16_rne(a0.w);
        af[4] = (short)f32_to_bf16_rne(a1.x);
        af[5] = (short)f32_to_bf16_rne(a1.y);
        af[6] = (short)f32_to_bf16_rne(a1.z);
        af[7] = (short)f32_to_bf16_rne(a1.w);
        afrag[s] = af;
    }

    float4v accs[4];
    #pragma unroll
    for (int which = 0; which < 4; which++) {
        float4v acc = {0.0f, 0.0f, 0.0f, 0.0f};
        int tile = which * 4 + w;
        #pragma unroll
        for (int s = 0; s < KS; s++) {
            short8 bfrag = *(const short8*)&Wp[((tile * KS + s) * 64 + lane) * 8];
            acc = __builtin_amdgcn_mfma_f32_16x16x32_bf16(afrag[s], bfrag, acc, 0, 0, 0);
        }
        accs[which] = acc;
    }

    float bqc = bq[col], bkc = bk[col], bvc = bv[col];
    int j = n16 & 3;                    // byte/half position within 4-channel word
    int mword = (col >> 2);             // 4-channel word index 0..15

    #pragma unroll
    for (int r = 0; r < 4; r++) {
        int node = n0 + quad * 4 + r;
        Qf[node * 64 + col] = (accs[0][r] + bqc) * scale;
        Sf[node * 64 + col] = accs[3][r];
        // fp8-pack K: 4 consecutive channels -> one dword, via shfl-OR
        unsigned int ku = f32_to_fp8_byte(accs[1][r] + bkc) << (8 * j);
        ku |= __shfl_xor(ku, 1); ku |= __shfl_xor(ku, 2);
        // fp16-pack V: 4 consecutive channels -> uint2 {c0|c1<<16, c2|c3<<16}
        unsigned int hb = (unsigned int)__half_as_ushort(__float2half_rn(accs[2][r] + bvc));
        unsigned int vx = (j < 2) ? (hb << (16 * j)) : 0u;
        unsigned int vy = (j >= 2) ? (hb << (16 * (j - 2))) : 0u;
        vx |= __shfl_xor(vx, 1); vx |= __shfl_xor(vx, 2);
        vy |= __shfl_xor(vy, 1); vy |= __shfl_xor(vy, 2);
        if (j == 0) {
            K8[node * 16 + mword] = ku;
            Vh[node * 16 + mword] = make_uint2(vx, vy);
        }
    }
}

template <int D>
__global__ __launch_bounds__(256) void qkvs_mfma_kernel(
        const float* __restrict__ h,
        const unsigned short* __restrict__ Wp,
        const float* __restrict__ bq, const float* __restrict__ bk,
        const float* __restrict__ bv, float scale,
        float* __restrict__ Qf, float* __restrict__ Sf,
        unsigned int* __restrict__ K8, uint2* __restrict__ Vh) {
    qkvs_body<D>(blockIdx.x, threadIdx.x, h, Wp, bq, bk, bv, scale, Qf, Sf, K8, Vh);
}

// ---------------------------------------------------------------------------
// Fused scatter + layer-0 QKVS (independent work; fills the CUs).
__global__ __launch_bounds__(256) void scatter_qkvs0_kernel(
        const int* __restrict__ src, const int* __restrict__ dst,
        const int* __restrict__ goff, int2* __restrict__ ebkt,
        const float* __restrict__ h, const unsigned short* __restrict__ Wp,
        const float* __restrict__ bq, const float* __restrict__ bk,
        const float* __restrict__ bv, float scale,
        float* __restrict__ Qf, float* __restrict__ Sf,
        unsigned int* __restrict__ K8, uint2* __restrict__ Vh) {
    __shared__ int hist[NBK];
    int t = threadIdx.x;
    if (blockIdx.x < SB) {
        int i = blockIdx.x;
        for (int k = t; k < NBK; k += 256) hist[k] = 0;
        __syncthreads();
        int e0 = i * EPB;
        #pragma unroll
        for (int r = 0; r < EPB / 256; r++) {
            int e = e0 + r * 256 + t;
            if (e < N_EDGES) {
                int s = src[e], d = dst[e];
                int k = d >> 8;
                int rank = atomicAdd(&hist[k], 1);
                ebkt[goff[k * SB + i] + rank] = make_int2(s, d);
            }
        }
    } else {
        qkvs_body<32>(blockIdx.x - SB, t, h, Wp, bq, bk, bv, scale, Qf, Sf, K8, Vh);
    }
}

__global__ __launch_bounds__(256) void bucket_build_kernel(
        const int2* __restrict__ ebkt, const int* __restrict__ bbase,
        int* __restrict__ row_ptr, int* __restrict__ colb) {
    __shared__ int ldeg[256];
    __shared__ int lcur[256];
    __shared__ int wsum[4];
    int b = blockIdx.x;
    int t = threadIdx.x;
    int cbase = bbase[b];
    int cnt = bbase[b + 1] - cbase;

    ldeg[t] = 0;
    __syncthreads();
    for (int i = t; i < cnt; i += 256) {
        int2 e = ebkt[cbase + i];
        atomicAdd(&ldeg[e.y & 255], 1);
    }
    __syncthreads();

    int lane = t & 63;
    int w = t >> 6;
    int v = ldeg[t];
    int incl = v;
    #pragma unroll
    for (int off = 1; off < 64; off <<= 1) {
        int tt = __shfl_up(incl, off);
        if (lane >= off) incl += tt;
    }
    if (lane == 63) wsum[w] = incl;
    __syncthreads();
    int woff = 0;
    #pragma unroll
    for (int k = 0; k < 4; k++) if (k < w) woff += wsum[k];
    int excl = woff + incl - v;

    int node = b * 256 + t;
    if (node < N_NODES) row_ptr[node] = cbase + excl;
    lcur[t] = excl;
    __syncthreads();

    for (int i = t; i < cnt; i += 256) {
        int2 e = ebkt[cbase + i];
        int r = atomicAdd(&lcur[e.y & 255], 1);
        colb[cbase + r] = e.x;
    }
}

// ---------------------------------------------------------------------------
// Kernel: per-node attention aggregation + skip + LayerNorm (+res/relu).
// One wave per node, 4 groups of 16 lanes; group g walks edges beg+g, +4, ...
// KEY CHANGE (R5): src index loaded DIRECTLY per group (16 lanes, same 4B
// address -> HW broadcast) — removes the colb preload + 4x ds_bpermute +
// limit-shuffle machinery per 16 edges (R4 showed agg time tracks wave
// instruction count x stall, not gather bytes). Chain: colb -> K/V (1 hop).
template <int HEADS, bool RES, bool RELU, bool HEAD>
__global__ __launch_bounds__(256) void agg_kernel(
                           const float* __restrict__ Qf,
                           const float* __restrict__ Sf,
                           const unsigned int* __restrict__ K8,
                           const uint2* __restrict__ Vh,
                           const int* __restrict__ row_ptr, const int* __restrict__ colb,
                           const float* __restrict__ g, const float* __restrict__ b,
                           const float* __restrict__ h_in, float* __restrict__ h_out,
                           const float* __restrict__ Wr1, const float* __restrict__ br1,
                           const float* __restrict__ Wr2, const float* __restrict__ br2,
                           const float* __restrict__ Wt1, const float* __restrict__ bt1,
                           const float* __restrict__ Wt2, const float* __restrict__ bt2,
                           float* __restrict__ out) {
    constexpr int C = HID / HEADS;
    int lane = threadIdx.x & 63;
    int m = lane & 15;
    int grp = lane >> 4;
    int n = blockIdx.x * 4 + (threadIdx.x >> 6);

    float4 q4 = *(const float4*)&Qf[n * 64 + 4 * m];

    int beg = row_ptr[n], end = row_ptr[n + 1];

    float ssum = 0.0f;
    float acc0 = 0.0f, acc1 = 0.0f, acc2 = 0.0f, acc3 = 0.0f;

    for (int i0 = beg + grp; i0 < end; i0 += 8) {
        #pragma unroll
        for (int u = 0; u < 2; u++) {
            int idx = i0 + u * 4;
            bool ok = idx < end;                  // uniform within the group
            int s = ok ? colb[idx] : 0;           // 16-lane same-addr broadcast
            unsigned int kw = K8[(size_t)s * 16 + m];
            uint2 vw = Vh[(size_t)s * 16 + m];

            float2v ka = fp8x2_to_f32<false>(kw);
            float2v kb = fp8x2_to_f32<true>(kw);
            float t = fmaf(q4.x, ka.x, fmaf(q4.y, ka.y,
                      fmaf(q4.z, kb.x, q4.w * kb.y)));
            #pragma unroll
            for (int off = 1; off < C / 4; off <<= 1) t += __shfl_xor(t, off);
            float pv = ok ? __expf(t) : 0.0f;
            ssum += pv;

            float2 v0 = h2_to_f32(vw.x), v1 = h2_to_f32(vw.y);
            acc0 = fmaf(pv, v0.x, acc0);
            acc1 = fmaf(pv, v0.y, acc1);
            acc2 = fmaf(pv, v1.x, acc2);
            acc3 = fmaf(pv, v1.y, acc3);
        }
    }

    #pragma unroll
    for (int off = 16; off < 64; off <<= 1) {
        ssum += __shfl_xor(ssum, off);
        acc0 += __shfl_xor(acc0, off);
        acc1 += __shfl_xor(acc1, off);
        acc2 += __shfl_xor(acc2, off);
        acc3 += __shfl_xor(acc3, off);
    }

    float inv = 1.0f / (ssum + 1e-16f);
    float4 sv = *(const float4*)&Sf[n * 64 + 4 * m];
    float o0 = fmaf(acc0, inv, sv.x);
    float o1 = fmaf(acc1, inv, sv.y);
    float o2 = fmaf(acc2, inv, sv.z);
    float o3 = fmaf(acc3, inv, sv.w);

    float s = (o0 + o1) + (o2 + o3);
    #pragma unroll
    for (int off = 1; off < 16; off <<= 1) s += __shfl_xor(s, off);
    float mu = s * (1.0f / 64.0f);
    float d0 = o0 - mu, d1 = o1 - mu, d2 = o2 - mu, d3 = o3 - mu;
    float vs = (d0 * d0 + d1 * d1) + (d2 * d2 + d3 * d3);
    #pragma unroll
    for (int off = 1; off < 16; off <<= 1) vs += __shfl_xor(vs, off);
    float rstd = rsqrtf(vs * (1.0f / 64.0f) + 1e-5f);

    float4 gv = *(const float4*)&g[4 * m];
    float4 bv = *(const float4*)&b[4 * m];
    float y0 = d0 * rstd * gv.x + bv.x;
    float y1 = d1 * rstd * gv.y + bv.y;
    float y2 = d2 * rstd * gv.z + bv.z;
    float y3 = d3 * rstd * gv.w + bv.w;
    if (RES) {
        float4 rv = *(const float4*)&h_in[n * 64 + 4 * m];
        y0 = fmaf(0.1f, rv.x, y0);
        y1 = fmaf(0.1f, rv.y, y1);
        y2 = fmaf(0.1f, rv.z, y2);
        y3 = fmaf(0.1f, rv.w, y3);
    }
    if (RELU) {
        y0 = fmaxf(y0, 0.0f); y1 = fmaxf(y1, 0.0f);
        y2 = fmaxf(y2, 0.0f); y3 = fmaxf(y3, 0.0f);
    }

    if (!HEAD) {
        if (grp == 0) {
            float4 yv = make_float4(y0, y1, y2, y3);
            *(float4*)&h_out[n * 64 + 4 * m] = yv;
        }
    } else {
        __shared__ float sh[4][HID];
        int wave = threadIdx.x >> 6;
        if (grp == 0) {
            float4 yv = make_float4(y0, y1, y2, y3);
            *(float4*)&sh[wave][4 * m] = yv;
        }
        __syncthreads();
        int half = lane >> 5;
        int j = lane & 31;
        const float* W1 = half ? Wt1 : Wr1;
        const float* b1 = half ? bt1 : br1;
        const float* W2 = half ? Wt2 : Wr2;
        const float* b2v = half ? bt2 : br2;
        float a = b1[j];
        #pragma unroll 8
        for (int i = 0; i < 64; i++) a = fmaf(sh[wave][i], W1[i * 32 + j], a);
        a = fmaxf(a, 0.0f);
        float r = a * W2[j];
        #pragma unroll
        for (int off = 1; off < 32; off <<= 1) r += __shfl_xor(r, off);
        if (j == 0) out[n * 2 + half] = r + b2v[0];
    }
}

// ---------------------------------------------------------------------------
extern "C" void kernel_launch(void* const* d_in, const int* in_sizes, int n_in,
                              void* d_out, int out_size, void* d_ws, size_t ws_size,
                              hipStream_t stream) {
    const float* x    = (const float*)d_in[0];
    const int*   ei   = (const int*)d_in[1];
    const int*   src  = ei;
    const int*   dst  = ei + N_EDGES;
    const float* ln0g = (const float*)d_in[2];
    const float* ln0b = (const float*)d_in[3];

    const float* P[27];
    for (int i = 0; i < 27; i++) P[i] = (const float*)d_in[4 + i];
    const float* Wr1 = (const float*)d_in[31];
    const float* br1 = (const float*)d_in[32];
    const float* Wr2 = (const float*)d_in[33];
    const float* br2 = (const float*)d_in[34];
    const float* Wt1 = (const float*)d_in[35];
    const float* bt1 = (const float*)d_in[36];
    const float* Wt2 = (const float*)d_in[37];
    const float* bt2 = (const float*)d_in[38];

    float* out = (float*)d_out;

    // workspace layout
    float* hbuf0 = (float*)d_ws;                 // N*64
    float* hbuf1 = hbuf0 + N_NODES * 64;         // N*64
    float* Qf    = hbuf1 + N_NODES * 64;         // N*64 f32
    float* Sf    = Qf + N_NODES * 64;            // N*64 f32
    unsigned int* K8 = (unsigned int*)(Sf + N_NODES * 64);  // N*16 uint (64B fp8 rows)
    uint2* Vh    = (uint2*)(K8 + N_NODES * 16);  // N*16 uint2 (128B fp16 rows)
    int* row_ptr = (int*)(Vh + N_NODES * 16);    // N+1
    int* colb    = row_ptr + (N_NODES + 1);      // E
    int* ghist   = colb + N_EDGES;               // FLAT
    int* goff    = ghist + FLAT;                 // FLAT
    int* csum    = goff + FLAT;                  // SCAN_B
    int* coff    = csum + SCAN_B;                // SCAN_B
    int* bbase   = coff + SCAN_B;                // NBK+1
    unsigned short* Wp0 = (unsigned short*)(bbase + NBK + 1); // 16*1*512
    unsigned short* Wp1 = Wp0 + 16 * 1 * 512;                 // 16*2*512
    unsigned short* Wp2 = Wp1 + 16 * 2 * 512;                 // 16*2*512
    // ebkt aliases hbuf1 (dead until agg0 writes it): E int2 = 6.4 MB < 12.8 MB
    int2* ebkt = (int2*)hbuf1;

    // ---- fused prep (ln0 + bucket hist + weight packs) ----
    prep_kernel<<<PREP_BLKS, 256, 0, stream>>>(x, ln0g, ln0b, hbuf0,
        dst, ghist,
        P[0],  P[2],  P[4],  P[6],  Wp0,
        P[9],  P[11], P[13], P[15], Wp1,
        P[18], P[20], P[22], P[24], Wp2);
    // ---- CSR build (deterministic counting sort, separate kernels) ----
    scan1_kernel<<<SCAN_B, 256, 0, stream>>>(ghist, csum);
    scan2_kernel<<<1, 64, 0, stream>>>(csum, coff, bbase, row_ptr);
    scan3_kernel<<<SCAN_B, 256, 0, stream>>>(ghist, coff, goff, bbase);
    // ---- scatter + layer-0 QKVS fused (independent work, fills the CUs) ----
    scatter_qkvs0_kernel<<<SB + QKVS0_BLKS, 256, 0, stream>>>(src, dst, goff, ebkt,
        hbuf0, Wp0, P[1], P[3], P[5], 0.25f, Qf, Sf, K8, Vh);
    bucket_build_kernel<<<NBK, 256, 0, stream>>>(ebkt, bbase, row_ptr, colb);

    // ---- layer 0: 32 -> 64, heads=4, no residual, relu ----
    agg_kernel<4, false, true, false><<<12500, 256, 0, stream>>>(Qf, Sf, K8, Vh,
        row_ptr, colb, P[7], P[8], nullptr, hbuf1,
        Wr1, br1, Wr2, br2, Wt1, bt1, Wt2, bt2, out);

    // ---- layer 1: 64 -> 64, heads=4, residual, relu ----
    qkvs_mfma_kernel<64><<<3125, 256, 0, stream>>>(hbuf1, Wp1,
        P[10], P[12], P[14], 0.25f, Qf, Sf, K8, Vh);
    agg_kernel<4, true, true, false><<<12500, 256, 0, stream>>>(Qf, Sf, K8, Vh,
        row_ptr, colb, P[16], P[17], hbuf1, hbuf0,
        Wr1, br1, Wr2, br2, Wt1, bt1, Wt2, bt2, out);

    // ---- layer 2: 64 -> 64, heads=1, residual, no relu + fused MLP heads ----
    qkvs_mfma_kernel<64><<<3125, 256, 0, stream>>>(hbuf0, Wp2,
        P[19], P[21], P[23], 0.125f, Qf, Sf, K8, Vh);
    agg_kernel<1, true, false, true><<<12500, 256, 0, stream>>>(Qf, Sf, K8, Vh,
        row_ptr, colb, P[25], P[26], hbuf0, hbuf1,
        Wr1, br1, Wr2, br2, Wt1, bt1, Wt2, bt2, out);
}